// Round 14
// baseline (449.620 us; speedup 1.0000x reference)
//
#include <hip/hip_runtime.h>
#include <hip/hip_bf16.h>
#include <hip/hip_cooperative_groups.h>

namespace cg = cooperative_groups;

#define BB 8
#define NN 1024
#define FIN 512
#define HH 8
#define FOUT 64
#define HF 512
#define SLOPE 0.2f
#define ECAP 64

typedef __attribute__((ext_vector_type(8))) short bf16x8;
typedef __attribute__((ext_vector_type(4))) float f32x4;
typedef __attribute__((ext_vector_type(2))) float f32x2;
typedef unsigned long long ull;

static __device__ __forceinline__ float lrelu(float v) { return v > 0.0f ? v : SLOPE * v; }

static __device__ __forceinline__ unsigned short f2bf(float f) {
  __hip_bfloat16 h = __float2bfloat16(f);
  return *reinterpret_cast<unsigned short*>(&h);
}
static __device__ __forceinline__ float bflo(unsigned v) {
  unsigned u = v << 16;
  return *reinterpret_cast<float*>(&u);
}
static __device__ __forceinline__ float bfhi(unsigned v) {
  unsigned u = v & 0xffff0000u;
  return *reinterpret_cast<float*>(&u);
}
static __device__ __forceinline__ f32x2 unpk(unsigned q) {
  f32x2 r;
  r.x = bflo(q);
  r.y = bfhi(q);
  return r;
}

// ---------------------------------------------------------------------------
// Fused cooperative kernel: [P] detect + W-pack | grid.sync | [G] MFMA GEMM
// + e_src/e_dst | grid.sync | [A] sparse attention + skip + LayerNorm.
// Built for 8 blocks/CU residency: <=64 VGPR (launch_bounds), 17.4KB LDS.
// ---------------------------------------------------------------------------
__global__ __launch_bounds__(256, 8) void k_fused(
    const float* __restrict__ x, const void* __restrict__ adj,
    const float* __restrict__ W, const float* __restrict__ a,
    const float* __restrict__ gamma, const float* __restrict__ beta,
    float* __restrict__ out, int* __restrict__ flag,
    unsigned short* __restrict__ Wh, unsigned short* __restrict__ Wt2,
    float* __restrict__ e_src, float* __restrict__ e_dst) {
  __shared__ union {
    struct { float tile[32][65]; } prep;                       // 8.3 KB
    struct { short As[2][32 * 128];                            // 16 KB
             float eps[2][2][32], epd[2][2][32]; } g;          // +1 KB
    struct { unsigned short nbrs[4][NN];                       // 8 KB
             float edbuf[4][ECAP * 8];                         // 8 KB
             float esb[4][8], erm[4][8], einv[4][8]; } at;     // +384 B
  } L;

  cg::grid_group grid = cg::this_grid();
  const int t = threadIdx.x;
  const int wave = t >> 6, lane = t & 63;

  // ================= phase P: adjacency detect + W pack =================
  if (blockIdx.x == 0 && t < 64) {
    const int d = t * (NN + 1);
    const bool oki = ((const int*)adj)[d] == 1;
    const bool okf = ((const float*)adj)[d] == 1.0f;
    const ull mi = __ballot(oki), mf = __ballot(okf);
    if (t == 0) *flag = (mi == ~0ull) ? 1 : ((mf == ~0ull) ? 2 : 0);
  }
  for (int unit = blockIdx.x; unit < 128; unit += gridDim.x) {
    const int ks = unit & 15, h = unit >> 4;
    const int k0 = ks * 32, c0 = h * 64;
#pragma unroll
    for (int p = 0; p < 8; ++p) {
      const int r = (t >> 6) + p * 4, c = t & 63;
      L.prep.tile[r][c] = W[(size_t)(k0 + r) * HF + c0 + c];
    }
    __syncthreads();
    const int col_local = wave * 16 + (lane & 15);
    const int k_local = (lane >> 4) * 8;
    bf16x8 pk;
    unsigned short* u = (unsigned short*)&pk;
#pragma unroll
    for (int j = 0; j < 8; ++j) u[j] = f2bf(L.prep.tile[k_local + j][col_local]);
    *(bf16x8*)(Wt2 + ((size_t)((h * 16 + ks) * 4 + wave)) * 512 + lane * 8) = pk;
  }
  __threadfence();
  grid.sync();

  // ================= phase G: GEMM (unit = 32 rows x 2 heads) ============
  // wave tile 32x32: head = hp*2 + (wave>>1), col-half nh = wave&1.
  for (int unit = blockIdx.x; unit < 1024; unit += gridDim.x) {
    const int rt = unit >> 2, hp = unit & 3;
    const int row0 = rt * 32;
    const int head = hp * 2 + (wave >> 1);
    const int nh = wave & 1;
    const int col0 = head * 64 + nh * 32;
    const int lr = lane & 15, kq = lane >> 4;

    const int srow = t >> 3, sc2 = (t & 7) * 2;
    const float* xrow = x + (size_t)(row0 + srow) * FIN + sc2 * 8;
    const int sb0 = srow * 128 + ((sc2 + 0) ^ (srow & 7)) * 8;
    const int sb1 = srow * 128 + ((sc2 + 1) ^ (srow & 7)) * 8;

    f32x4 acc[2][2] = {};

    float4 r0, r1, r2, r3;
    {
      const float4* gp = (const float4*)xrow;
      r0 = gp[0]; r1 = gp[1]; r2 = gp[2]; r3 = gp[3];
    }

    __syncthreads();  // prior LDS use (prep / previous unit) complete
    int cur = 0;
    for (int step = 0; step < 4; ++step) {
      {
        bf16x8 p0, p1;
        unsigned short* u0 = (unsigned short*)&p0;
        unsigned short* u1 = (unsigned short*)&p1;
        u0[0] = f2bf(r0.x); u0[1] = f2bf(r0.y); u0[2] = f2bf(r0.z); u0[3] = f2bf(r0.w);
        u0[4] = f2bf(r1.x); u0[5] = f2bf(r1.y); u0[6] = f2bf(r1.z); u0[7] = f2bf(r1.w);
        u1[0] = f2bf(r2.x); u1[1] = f2bf(r2.y); u1[2] = f2bf(r2.z); u1[3] = f2bf(r2.w);
        u1[4] = f2bf(r3.x); u1[5] = f2bf(r3.y); u1[6] = f2bf(r3.z); u1[7] = f2bf(r3.w);
        *(bf16x8*)(&L.g.As[cur][sb0]) = p0;
        *(bf16x8*)(&L.g.As[cur][sb1]) = p1;
      }
      if (step < 3) {
        const float4* gp = (const float4*)(xrow + (step + 1) * 128);
        r0 = gp[0]; r1 = gp[1]; r2 = gp[2]; r3 = gp[3];
      }
      __syncthreads();

      const unsigned short* bbase =
          Wt2 + (((size_t)head * 16 + step * 4) * 4 + nh * 2) * 512 + lane * 8;
#pragma unroll
      for (int ks = 0; ks < 4; ++ks) {
        bf16x8 b0 = *(const bf16x8*)(bbase + (size_t)(ks * 4 + 0) * 512);
        bf16x8 b1 = *(const bf16x8*)(bbase + (size_t)(ks * 4 + 1) * 512);
        bf16x8 af[2];
#pragma unroll
        for (int m = 0; m < 2; ++m) {
          const int row = m * 16 + lr;
          af[m] = *(const bf16x8*)(&L.g.As[cur][row * 128 + ((ks * 4 + kq) ^ (row & 7)) * 8]);
        }
        acc[0][0] = __builtin_amdgcn_mfma_f32_16x16x32_bf16(af[0], b0, acc[0][0], 0, 0, 0);
        acc[0][1] = __builtin_amdgcn_mfma_f32_16x16x32_bf16(af[0], b1, acc[0][1], 0, 0, 0);
        acc[1][0] = __builtin_amdgcn_mfma_f32_16x16x32_bf16(af[1], b0, acc[1][0], 0, 0, 0);
        acc[1][1] = __builtin_amdgcn_mfma_f32_16x16x32_bf16(af[1], b1, acc[1][1], 0, 0, 0);
      }
      cur ^= 1;
      __syncthreads();
    }

    // Wh store (C/D: col=lane&15, row=kq*4+r)
#pragma unroll
    for (int m = 0; m < 2; ++m)
#pragma unroll
      for (int n = 0; n < 2; ++n)
#pragma unroll
        for (int r = 0; r < 4; ++r) {
          const int row = row0 + m * 16 + kq * 4 + r;
          const int col = col0 + n * 16 + lr;
          Wh[(size_t)row * HF + col] = f2bf(acc[m][n][r]);
        }

    // e_src/e_dst: per-wave 32-col partials, LDS-combined across col-halves
    float av_s[2], av_d[2];
#pragma unroll
    for (int n = 0; n < 2; ++n) {
      const int cl = nh * 32 + n * 16 + lr;  // col within head
      av_s[n] = a[head * 2 * FOUT + cl];
      av_d[n] = a[head * 2 * FOUT + FOUT + cl];
    }
#pragma unroll
    for (int m = 0; m < 2; ++m)
#pragma unroll
      for (int r = 0; r < 4; ++r) {
        float ps = acc[m][0][r] * av_s[0] + acc[m][1][r] * av_s[1];
        float pd = acc[m][0][r] * av_d[0] + acc[m][1][r] * av_d[1];
#pragma unroll
        for (int s = 1; s < 16; s <<= 1) {
          ps += __shfl_xor(ps, s);
          pd += __shfl_xor(pd, s);
        }
        if (lr == 0) {
          const int rowl = m * 16 + kq * 4 + r;
          L.g.eps[wave >> 1][nh][rowl] = ps;
          L.g.epd[wave >> 1][nh][rowl] = pd;
        }
      }
    __syncthreads();
    if (t < 64) {
      const int hl = t >> 5, row = t & 31;
      e_src[(size_t)(row0 + row) * HH + hp * 2 + hl] =
          L.g.eps[hl][0][row] + L.g.eps[hl][1][row];
      e_dst[(size_t)(row0 + row) * HH + hp * 2 + hl] =
          L.g.epd[hl][0][row] + L.g.epd[hl][1][row];
    }
    __syncthreads();
  }
  __threadfence();
  grid.sync();

  // ================= phase A: attention + skip + LayerNorm ===============
  const int mode = *flag;
  for (int unit = blockIdx.x; unit < 2048; unit += gridDim.x) {
    const int nbid = (unit & 7) * 256 + (unit >> 3);  // XCD-batch alignment
    const int gr = nbid * 4 + wave;
    const int bN = (gr >> 10) << 10;
    const size_t arow = (size_t)gr << 10;

    unsigned short* nb = L.at.nbrs[wave];
    float* ed = L.at.edbuf[wave];

    // phase 1: in-wave neighbor compaction
    int off = 0;
#pragma unroll
    for (int rr = 0; rr < 4; ++rr) {
      const int j0 = rr * 256 + lane * 4;
      bool v0, v1, v2, v3;
      if (mode == 1) {
        int4 q = *((const int4*)((const int*)adj + arow + j0));
        v0 = q.x != 0; v1 = q.y != 0; v2 = q.z != 0; v3 = q.w != 0;
      } else if (mode == 2) {
        float4 q = *((const float4*)((const float*)adj + arow + j0));
        v0 = q.x != 0.f; v1 = q.y != 0.f; v2 = q.z != 0.f; v3 = q.w != 0.f;
      } else {
        unsigned q = *((const unsigned*)((const unsigned char*)adj + arow + j0));
        v0 = (q & 0xffu) != 0; v1 = (q & 0xff00u) != 0;
        v2 = (q & 0xff0000u) != 0; v3 = (q >> 24) != 0;
      }
      ull m0 = __ballot(v0), m1 = __ballot(v1);
      ull m2 = __ballot(v2), m3 = __ballot(v3);
      const ull below = (1ull << lane) - 1ull;
      int base = off + __popcll(m0 & below) + __popcll(m1 & below) +
                 __popcll(m2 & below) + __popcll(m3 & below);
      int c = 0;
      if (v0) nb[base + c++] = (unsigned short)(j0 + 0);
      if (v1) nb[base + c++] = (unsigned short)(j0 + 1);
      if (v2) nb[base + c++] = (unsigned short)(j0 + 2);
      if (v3) nb[base + c++] = (unsigned short)(j0 + 3);
      off += __popcll(m0) + __popcll(m1) + __popcll(m2) + __popcll(m3);
    }
    const int total = off;
    const int ncap = total < ECAP ? total : ECAP;

    // phase 2: softmax stats (all 8 heads in parallel)
    const int h = lane & 7, kq = lane >> 3;
    for (int k = kq; k < ncap; k += 8)
      ed[k * 8 + h] = e_dst[(size_t)(bN + nb[k]) * HH + h];

    const float es = e_src[(size_t)gr * HH + h];
    float mx = -1e30f;
    for (int k = kq; k < total; k += 8) {
      float v = (k < ECAP) ? ed[k * 8 + h] : e_dst[(size_t)(bN + nb[k]) * HH + h];
      mx = fmaxf(mx, v);
    }
    mx = fmaxf(mx, __shfl_xor(mx, 8));
    mx = fmaxf(mx, __shfl_xor(mx, 16));
    mx = fmaxf(mx, __shfl_xor(mx, 32));
    const float rm = lrelu(es + mx);

    float z = 0.0f;
    for (int k = kq; k < total; k += 8) {
      float v = (k < ECAP) ? ed[k * 8 + h] : e_dst[(size_t)(bN + nb[k]) * HH + h];
      float w = __expf(lrelu(es + v) - rm);
      if (k < ECAP) ed[k * 8 + h] = w;
      z += w;
    }
    z += __shfl_xor(z, 8);
    z += __shfl_xor(z, 16);
    z += __shfl_xor(z, 32);
    if (kq == 0) {
      L.at.esb[wave][h] = es;
      L.at.erm[wave][h] = rm;
      L.at.einv[wave][h] = 1.0f / z;
    }

    // phase 3: weighted accumulation (packed f32, 6-wide groups)
    const int h2 = lane >> 3;
    const float es2 = L.at.esb[wave][h2], rm2 = L.at.erm[wave][h2];
    const int feat = lane * 8;
    const unsigned short* whB = Wh + (size_t)bN * HF + feat;

    const size_t xo = (size_t)gr * HF + feat;
    const float4 xv0 = *(const float4*)(x + xo);
    const float4 xv1 = *(const float4*)(x + xo + 4);

    f32x2 ac0 = {0.f, 0.f}, ac1 = {0.f, 0.f}, ac2 = {0.f, 0.f}, ac3 = {0.f, 0.f};

#define GAT_STEP(qq, ww)      \
  {                           \
    f32x2 w2;                 \
    w2.x = (ww); w2.y = (ww); \
    ac0 += w2 * unpk((qq).x); \
    ac1 += w2 * unpk((qq).y); \
    ac2 += w2 * unpk((qq).z); \
    ac3 += w2 * unpk((qq).w); \
  }

    int k = 0;
    for (; k + 6 <= ncap; k += 6) {
      const unsigned j0 = nb[k + 0], j1 = nb[k + 1], j2 = nb[k + 2];
      const unsigned j3 = nb[k + 3], j4 = nb[k + 4], j5 = nb[k + 5];
      uint4 q0 = *(const uint4*)(whB + (size_t)j0 * HF);
      uint4 q1 = *(const uint4*)(whB + (size_t)j1 * HF);
      uint4 q2 = *(const uint4*)(whB + (size_t)j2 * HF);
      uint4 q3 = *(const uint4*)(whB + (size_t)j3 * HF);
      uint4 q4 = *(const uint4*)(whB + (size_t)j4 * HF);
      uint4 q5 = *(const uint4*)(whB + (size_t)j5 * HF);
      const float w0 = ed[(k + 0) * 8 + h2], w1 = ed[(k + 1) * 8 + h2];
      const float w2_ = ed[(k + 2) * 8 + h2], w3 = ed[(k + 3) * 8 + h2];
      const float w4 = ed[(k + 4) * 8 + h2], w5 = ed[(k + 5) * 8 + h2];
      GAT_STEP(q0, w0); GAT_STEP(q1, w1); GAT_STEP(q2, w2_);
      GAT_STEP(q3, w3); GAT_STEP(q4, w4); GAT_STEP(q5, w5);
    }
    for (; k < ncap; ++k) {
      const unsigned j = nb[k];
      const float w = ed[k * 8 + h2];
      uint4 q = *(const uint4*)(whB + (size_t)j * HF);
      GAT_STEP(q, w);
    }
    for (; k < total; ++k) {  // rare tail beyond ECAP (exact)
      const unsigned j = nb[k];
      const float w = __expf(lrelu(es2 + e_dst[(size_t)(bN + j) * HH + h2]) - rm2);
      uint4 q = *(const uint4*)(whB + (size_t)j * HF);
      GAT_STEP(q, w);
    }
#undef GAT_STEP
    const float inv = L.at.einv[wave][h2];

    // phase 4: skip + LayerNorm
    float v0 = ac0.x * inv + xv0.x, v1 = ac0.y * inv + xv0.y;
    float v2 = ac1.x * inv + xv0.z, v3 = ac1.y * inv + xv0.w;
    float v4 = ac2.x * inv + xv1.x, v5 = ac2.y * inv + xv1.y;
    float v6 = ac3.x * inv + xv1.z, v7 = ac3.y * inv + xv1.w;

    float s = v0 + v1 + v2 + v3 + v4 + v5 + v6 + v7;
    float ss = v0 * v0 + v1 * v1 + v2 * v2 + v3 * v3 +
               v4 * v4 + v5 * v5 + v6 * v6 + v7 * v7;
#pragma unroll
    for (int sft = 1; sft < 64; sft <<= 1) {
      s += __shfl_xor(s, sft);
      ss += __shfl_xor(ss, sft);
    }
    const float mu = s * (1.0f / 512.0f);
    const float var = ss * (1.0f / 512.0f) - mu * mu;
    const float rstd = rsqrtf(var + 1e-5f);

    float4 g0 = *(const float4*)(gamma + feat);
    float4 g1 = *(const float4*)(gamma + feat + 4);
    float4 b0 = *(const float4*)(beta + feat);
    float4 b1 = *(const float4*)(beta + feat + 4);
    float4 o0, o1;
    o0.x = (v0 - mu) * rstd * g0.x + b0.x;
    o0.y = (v1 - mu) * rstd * g0.y + b0.y;
    o0.z = (v2 - mu) * rstd * g0.z + b0.z;
    o0.w = (v3 - mu) * rstd * g0.w + b0.w;
    o1.x = (v4 - mu) * rstd * g1.x + b1.x;
    o1.y = (v5 - mu) * rstd * g1.y + b1.y;
    o1.z = (v6 - mu) * rstd * g1.z + b1.z;
    o1.w = (v7 - mu) * rstd * g1.w + b1.w;
    *(float4*)(out + xo) = o0;
    *(float4*)(out + xo + 4) = o1;
  }
}

extern "C" void kernel_launch(void* const* d_in, const int* in_sizes, int n_in,
                              void* d_out, int out_size, void* d_ws,
                              size_t ws_size, hipStream_t stream) {
  const float* x = (const float*)d_in[0];
  const void* adj = d_in[1];
  const float* W = (const float*)d_in[2];
  const float* a = (const float*)d_in[3];
  const float* gamma = (const float*)d_in[4];
  const float* beta = (const float*)d_in[5];
  float* out = (float*)d_out;

  char* ws = (char*)d_ws;
  int* flag = (int*)ws;
  unsigned short* Wh = (unsigned short*)(ws + 256);                // 8 MB
  unsigned short* Wt2 = (unsigned short*)(ws + 256 + 8388608);     // 512 KB
  float* e_src = (float*)(ws + 256 + 8388608 + 524288);            // 256 KB
  float* e_dst = e_src + (size_t)BB * NN * HH;                     // 256 KB

  // occupancy-safe cooperative grid (deterministic query, clamped to work)
  int nb = 0;
  hipOccupancyMaxActiveBlocksPerMultiprocessor(&nb, k_fused, 256, 0);
  if (nb < 1) nb = 1;
  long long g = (long long)nb * 256;  // 256 CUs on MI355X
  if (g > 2048) g = 2048;
  dim3 gridDim3((unsigned)g), blockDim3(256);

  void* args[] = {(void*)&x,     (void*)&adj,  (void*)&W,    (void*)&a,
                  (void*)&gamma, (void*)&beta, (void*)&out,  (void*)&flag,
                  (void*)&Wh,    (void*)&Wt2,  (void*)&e_src, (void*)&e_dst};
  hipLaunchCooperativeKernel((void*)k_fused, gridDim3, blockDim3, args, 0,
                             stream);
}

// Round 15
// 46.396 us; speedup vs baseline: 9.6909x; 9.6909x over previous
//
#include <hip/hip_runtime.h>
#include <hip/hip_bf16.h>

#define BB 8
#define NN 1024
#define FIN 512
#define HH 8
#define FOUT 64
#define HF 512
#define SLOPE 0.2f
#define ECAP 48

typedef __attribute__((ext_vector_type(8))) short bf16x8;
typedef __attribute__((ext_vector_type(4))) float f32x4;
typedef __attribute__((ext_vector_type(2))) float f32x2;
typedef unsigned long long ull;

static __device__ __forceinline__ float lrelu(float v) { return v > 0.0f ? v : SLOPE * v; }

static __device__ __forceinline__ unsigned short f2bf(float f) {
  __hip_bfloat16 h = __float2bfloat16(f);
  return *reinterpret_cast<unsigned short*>(&h);
}
static __device__ __forceinline__ float bflo(unsigned v) {
  unsigned u = v << 16;
  return *reinterpret_cast<float*>(&u);
}
static __device__ __forceinline__ float bfhi(unsigned v) {
  unsigned u = v & 0xffff0000u;
  return *reinterpret_cast<float*>(&u);
}
static __device__ __forceinline__ f32x2 unpk(unsigned q) {
  f32x2 r;
  r.x = bflo(q);
  r.y = bfhi(q);
  return r;
}

// ---------------------------------------------------------------------------
// K1: pack W into MFMA-fragment-ordered bf16 (byte-identical to R11).
// ---------------------------------------------------------------------------
__global__ __launch_bounds__(256) void k_prep2(const float* __restrict__ W,
                                               unsigned short* __restrict__ Wt2,
                                               const void* __restrict__ adj,
                                               int* __restrict__ flag) {
  if (blockIdx.x == 0 && blockIdx.y == 0 && threadIdx.x < 64) {
    const int i = threadIdx.x;
    const int d = i * (NN + 1);
    const bool oki = ((const int*)adj)[d] == 1;
    const bool okf = ((const float*)adj)[d] == 1.0f;
    const ull mi = __ballot(oki);
    const ull mf = __ballot(okf);
    if (i == 0) *flag = (mi == ~0ull) ? 1 : ((mf == ~0ull) ? 2 : 0);
  }

  __shared__ float tile[32][65];
  const int t = threadIdx.x;
  const int ks = blockIdx.x, h = blockIdx.y;
  const int k0 = ks * 32, c0 = h * 64;

#pragma unroll
  for (int p = 0; p < 8; ++p) {
    const int r = (t >> 6) + p * 4;
    const int c = t & 63;
    tile[r][c] = W[(size_t)(k0 + r) * HF + c0 + c];
  }
  __syncthreads();

  const int lane = t & 63, n = t >> 6;
  const int col_local = n * 16 + (lane & 15);
  const int k_local = (lane >> 4) * 8;
  bf16x8 pk;
  unsigned short* u = (unsigned short*)&pk;
#pragma unroll
  for (int j = 0; j < 8; ++j) u[j] = f2bf(tile[k_local + j][col_local]);
  *(bf16x8*)(Wt2 + ((size_t)((h * 16 + ks) * 4 + n)) * 512 + lane * 8) = pk;
}

// ---------------------------------------------------------------------------
// K2: Wh = x @ W via bf16 MFMA, packed-B layout. (byte-identical to R11)
// ---------------------------------------------------------------------------
__global__ __launch_bounds__(256) void k_gemm4(
    const float* __restrict__ x, const unsigned short* __restrict__ Wt2,
    const float* __restrict__ a, unsigned short* __restrict__ Wh,
    float* __restrict__ e_src, float* __restrict__ e_dst) {
  __shared__ short As[2][32 * 128];

  const int t = threadIdx.x;
  const int wave = t >> 6, lane = t & 63;
  const int row0 = blockIdx.x * 32;
  const int head = blockIdx.y * 4 + wave;
  const int col0 = head * 64;
  const int lr = lane & 15, kq = lane >> 4;

  const unsigned short* wt2h = Wt2 + (size_t)head * 16 * 4 * 512 + lane * 8;

  const int srow = t >> 3;
  const int sc2 = (t & 7) * 2;
  const float* xrow = x + (size_t)(row0 + srow) * FIN + sc2 * 8;
  const int sbyte0 = srow * 128 + ((sc2 + 0) ^ (srow & 7)) * 8;
  const int sbyte1 = srow * 128 + ((sc2 + 1) ^ (srow & 7)) * 8;

  f32x4 acc[2][4] = {};

  float4 r0, r1, r2, r3;
  {
    const float4* g = (const float4*)(xrow);
    r0 = g[0]; r1 = g[1]; r2 = g[2]; r3 = g[3];
  }

  int cur = 0;
  for (int step = 0; step < 4; ++step) {
    {
      bf16x8 p0, p1;
      unsigned short* u0 = (unsigned short*)&p0;
      unsigned short* u1 = (unsigned short*)&p1;
      u0[0] = f2bf(r0.x); u0[1] = f2bf(r0.y); u0[2] = f2bf(r0.z); u0[3] = f2bf(r0.w);
      u0[4] = f2bf(r1.x); u0[5] = f2bf(r1.y); u0[6] = f2bf(r1.z); u0[7] = f2bf(r1.w);
      u1[0] = f2bf(r2.x); u1[1] = f2bf(r2.y); u1[2] = f2bf(r2.z); u1[3] = f2bf(r2.w);
      u1[4] = f2bf(r3.x); u1[5] = f2bf(r3.y); u1[6] = f2bf(r3.z); u1[7] = f2bf(r3.w);
      *(bf16x8*)(&As[cur][sbyte0]) = p0;
      *(bf16x8*)(&As[cur][sbyte1]) = p1;
    }
    if (step < 3) {
      const float4* g = (const float4*)(xrow + (step + 1) * 128);
      r0 = g[0]; r1 = g[1]; r2 = g[2]; r3 = g[3];
    }

    bf16x8 bfr[4][4];
    {
      const unsigned short* bbase = wt2h + (size_t)(step * 4) * 4 * 512;
#pragma unroll
      for (int ks = 0; ks < 4; ++ks)
#pragma unroll
        for (int n = 0; n < 4; ++n)
          bfr[ks][n] = *(const bf16x8*)(bbase + (size_t)(ks * 4 + n) * 512);
    }
    __syncthreads();

#pragma unroll
    for (int ks = 0; ks < 4; ++ks) {
      bf16x8 af[2];
#pragma unroll
      for (int m = 0; m < 2; ++m) {
        const int row = m * 16 + lr;
        af[m] = *(const bf16x8*)(&As[cur][row * 128 + ((ks * 4 + kq) ^ (row & 7)) * 8]);
      }
#pragma unroll
      for (int n = 0; n < 4; ++n) {
        acc[0][n] = __builtin_amdgcn_mfma_f32_16x16x32_bf16(af[0], bfr[ks][n], acc[0][n], 0, 0, 0);
        acc[1][n] = __builtin_amdgcn_mfma_f32_16x16x32_bf16(af[1], bfr[ks][n], acc[1][n], 0, 0, 0);
      }
    }
    cur ^= 1;
  }

#pragma unroll
  for (int m = 0; m < 2; ++m)
#pragma unroll
    for (int n = 0; n < 4; ++n)
#pragma unroll
      for (int r = 0; r < 4; ++r) {
        const int row = row0 + m * 16 + kq * 4 + r;
        const int col = col0 + n * 16 + lr;
        Wh[(size_t)row * HF + col] = f2bf(acc[m][n][r]);
      }

  float av_s[4], av_d[4];
#pragma unroll
  for (int n = 0; n < 4; ++n) {
    const int cl = n * 16 + lr;
    av_s[n] = a[head * 2 * FOUT + cl];
    av_d[n] = a[head * 2 * FOUT + FOUT + cl];
  }
#pragma unroll
  for (int m = 0; m < 2; ++m)
#pragma unroll
    for (int r = 0; r < 4; ++r) {
      float ps = acc[m][0][r] * av_s[0] + acc[m][1][r] * av_s[1] +
                 acc[m][2][r] * av_s[2] + acc[m][3][r] * av_s[3];
      float pd = acc[m][0][r] * av_d[0] + acc[m][1][r] * av_d[1] +
                 acc[m][2][r] * av_d[2] + acc[m][3][r] * av_d[3];
#pragma unroll
      for (int s = 1; s < 16; s <<= 1) {
        ps += __shfl_xor(ps, s);
        pd += __shfl_xor(pd, s);
      }
      if (lr == 0) {
        const int row = row0 + m * 16 + kq * 4 + r;
        e_src[(size_t)row * HH + head] = ps;
        e_dst[(size_t)row * HH + head] = pd;
      }
    }
}

// ---------------------------------------------------------------------------
// K3: fused sparse attention + skip + LayerNorm.
// CHANGE vs R11: ECAP 64 -> 48 (saves 2 KB LDS) to fit 8 blocks/CU (was 7).
// deg = 33.7 +- 5.6, so ~99.7% of rows fit; exact e_dst-recompute tail
// covers the rest. Everything else identical to R11.
// ---------------------------------------------------------------------------
__global__ __launch_bounds__(256) void k_attn(
    const float* __restrict__ x, const void* __restrict__ adj,
    const int* __restrict__ flag, const unsigned short* __restrict__ Wh,
    const float* __restrict__ e_src, const float* __restrict__ e_dst,
    const float* __restrict__ gamma, const float* __restrict__ beta,
    float* __restrict__ out) {
  __shared__ unsigned short nbrs[4][NN];
  __shared__ float edbuf[4][ECAP * 8];
  __shared__ float esb[4][8], erm[4][8], einv[4][8];

  const int wave = threadIdx.x >> 6, lane = threadIdx.x & 63;
  const int bid = blockIdx.x;
  const int nbid = (bid & 7) * 256 + (bid >> 3);  // XCD-batch alignment
  const int gr = nbid * 4 + wave;
  const int bN = (gr >> 10) << 10;
  const size_t arow = (size_t)gr << 10;
  const int mode = *flag;

  unsigned short* nb = nbrs[wave];
  float* ed = edbuf[wave];

  // ---- phase 1: in-wave neighbor compaction ----
  int off = 0;
#pragma unroll
  for (int rr = 0; rr < 4; ++rr) {
    const int j0 = rr * 256 + lane * 4;
    bool v0, v1, v2, v3;
    if (mode == 1) {
      int4 q = *((const int4*)((const int*)adj + arow + j0));
      v0 = q.x != 0; v1 = q.y != 0; v2 = q.z != 0; v3 = q.w != 0;
    } else if (mode == 2) {
      float4 q = *((const float4*)((const float*)adj + arow + j0));
      v0 = q.x != 0.f; v1 = q.y != 0.f; v2 = q.z != 0.f; v3 = q.w != 0.f;
    } else {
      unsigned q = *((const unsigned*)((const unsigned char*)adj + arow + j0));
      v0 = (q & 0xffu) != 0; v1 = (q & 0xff00u) != 0;
      v2 = (q & 0xff0000u) != 0; v3 = (q >> 24) != 0;
    }
    ull m0 = __ballot(v0), m1 = __ballot(v1);
    ull m2 = __ballot(v2), m3 = __ballot(v3);
    const ull below = (1ull << lane) - 1ull;
    int base = off + __popcll(m0 & below) + __popcll(m1 & below) +
               __popcll(m2 & below) + __popcll(m3 & below);
    int c = 0;
    if (v0) nb[base + c++] = (unsigned short)(j0 + 0);
    if (v1) nb[base + c++] = (unsigned short)(j0 + 1);
    if (v2) nb[base + c++] = (unsigned short)(j0 + 2);
    if (v3) nb[base + c++] = (unsigned short)(j0 + 3);
    off += __popcll(m0) + __popcll(m1) + __popcll(m2) + __popcll(m3);
  }
  const int total = off;
  const int ncap = total < ECAP ? total : ECAP;

  // ---- phase 2: softmax stats for all 8 heads ----
  const int h = lane & 7, kq = lane >> 3;
  for (int k = kq; k < ncap; k += 8)
    ed[k * 8 + h] = e_dst[(size_t)(bN + nb[k]) * HH + h];

  const float es = e_src[(size_t)gr * HH + h];
  float mx = -1e30f;
  for (int k = kq; k < total; k += 8) {
    float v = (k < ECAP) ? ed[k * 8 + h] : e_dst[(size_t)(bN + nb[k]) * HH + h];
    mx = fmaxf(mx, v);
  }
  mx = fmaxf(mx, __shfl_xor(mx, 8));
  mx = fmaxf(mx, __shfl_xor(mx, 16));
  mx = fmaxf(mx, __shfl_xor(mx, 32));
  const float rm = lrelu(es + mx);

  float z = 0.0f;
  for (int k = kq; k < total; k += 8) {
    float v = (k < ECAP) ? ed[k * 8 + h] : e_dst[(size_t)(bN + nb[k]) * HH + h];
    float w = __expf(lrelu(es + v) - rm);
    if (k < ECAP) ed[k * 8 + h] = w;  // unscaled weight
    z += w;
  }
  z += __shfl_xor(z, 8);
  z += __shfl_xor(z, 16);
  z += __shfl_xor(z, 32);
  if (kq == 0) {
    esb[wave][h] = es;
    erm[wave][h] = rm;
    einv[wave][h] = 1.0f / z;
  }

  // ---- phase 3: weighted accumulation (packed f32, 6-wide groups) ----
  const int h2 = lane >> 3;
  const float es2 = esb[wave][h2], rm2 = erm[wave][h2];
  const int feat = lane * 8;
  const unsigned short* whB = Wh + (size_t)bN * HF + feat;

  // hoisted phase-4 row input: HBM latency hides under the gather loop
  const size_t xo = (size_t)gr * HF + feat;
  const float4 xv0 = *(const float4*)(x + xo);
  const float4 xv1 = *(const float4*)(x + xo + 4);

  f32x2 ac0 = {0.f, 0.f}, ac1 = {0.f, 0.f}, ac2 = {0.f, 0.f}, ac3 = {0.f, 0.f};

#define GAT_STEP(qq, ww)                      \
  {                                           \
    f32x2 w2;                                 \
    w2.x = (ww); w2.y = (ww);                 \
    ac0 += w2 * unpk((qq).x);                 \
    ac1 += w2 * unpk((qq).y);                 \
    ac2 += w2 * unpk((qq).z);                 \
    ac3 += w2 * unpk((qq).w);                 \
  }

  int k = 0;
  for (; k + 6 <= ncap; k += 6) {
    const unsigned j0 = nb[k + 0], j1 = nb[k + 1], j2 = nb[k + 2];
    const unsigned j3 = nb[k + 3], j4 = nb[k + 4], j5 = nb[k + 5];
    uint4 q0 = *(const uint4*)(whB + (size_t)j0 * HF);
    uint4 q1 = *(const uint4*)(whB + (size_t)j1 * HF);
    uint4 q2 = *(const uint4*)(whB + (size_t)j2 * HF);
    uint4 q3 = *(const uint4*)(whB + (size_t)j3 * HF);
    uint4 q4 = *(const uint4*)(whB + (size_t)j4 * HF);
    uint4 q5 = *(const uint4*)(whB + (size_t)j5 * HF);
    const float w0 = ed[(k + 0) * 8 + h2], w1 = ed[(k + 1) * 8 + h2];
    const float w2_ = ed[(k + 2) * 8 + h2], w3 = ed[(k + 3) * 8 + h2];
    const float w4 = ed[(k + 4) * 8 + h2], w5 = ed[(k + 5) * 8 + h2];
    GAT_STEP(q0, w0); GAT_STEP(q1, w1); GAT_STEP(q2, w2_);
    GAT_STEP(q3, w3); GAT_STEP(q4, w4); GAT_STEP(q5, w5);
  }
  for (; k < ncap; ++k) {
    const unsigned j = nb[k];
    const float w = ed[k * 8 + h2];
    uint4 q = *(const uint4*)(whB + (size_t)j * HF);
    GAT_STEP(q, w);
  }
  for (; k < total; ++k) {  // tail beyond ECAP (exact recompute)
    const unsigned j = nb[k];
    const float w = __expf(lrelu(es2 + e_dst[(size_t)(bN + j) * HH + h2]) - rm2);
    uint4 q = *(const uint4*)(whB + (size_t)j * HF);
    GAT_STEP(q, w);
  }
#undef GAT_STEP
  const float inv = einv[wave][h2];

  // ---- phase 4: skip + LayerNorm (512 feats across the wave) ----
  float v0 = ac0.x * inv + xv0.x, v1 = ac0.y * inv + xv0.y;
  float v2 = ac1.x * inv + xv0.z, v3 = ac1.y * inv + xv0.w;
  float v4 = ac2.x * inv + xv1.x, v5 = ac2.y * inv + xv1.y;
  float v6 = ac3.x * inv + xv1.z, v7 = ac3.y * inv + xv1.w;

  float s = v0 + v1 + v2 + v3 + v4 + v5 + v6 + v7;
  float ss = v0 * v0 + v1 * v1 + v2 * v2 + v3 * v3 +
             v4 * v4 + v5 * v5 + v6 * v6 + v7 * v7;
#pragma unroll
  for (int sft = 1; sft < 64; sft <<= 1) {
    s += __shfl_xor(s, sft);
    ss += __shfl_xor(ss, sft);
  }
  const float mu = s * (1.0f / 512.0f);
  const float var = ss * (1.0f / 512.0f) - mu * mu;
  const float rstd = rsqrtf(var + 1e-5f);

  float4 g0 = *(const float4*)(gamma + feat);
  float4 g1 = *(const float4*)(gamma + feat + 4);
  float4 b0 = *(const float4*)(beta + feat);
  float4 b1 = *(const float4*)(beta + feat + 4);
  float4 o0, o1;
  o0.x = (v0 - mu) * rstd * g0.x + b0.x;
  o0.y = (v1 - mu) * rstd * g0.y + b0.y;
  o0.z = (v2 - mu) * rstd * g0.z + b0.z;
  o0.w = (v3 - mu) * rstd * g0.w + b0.w;
  o1.x = (v4 - mu) * rstd * g1.x + b1.x;
  o1.y = (v5 - mu) * rstd * g1.y + b1.y;
  o1.z = (v6 - mu) * rstd * g1.z + b1.z;
  o1.w = (v7 - mu) * rstd * g1.w + b1.w;
  *(float4*)(out + xo) = o0;
  *(float4*)(out + xo + 4) = o1;
}

extern "C" void kernel_launch(void* const* d_in, const int* in_sizes, int n_in,
                              void* d_out, int out_size, void* d_ws,
                              size_t ws_size, hipStream_t stream) {
  const float* x = (const float*)d_in[0];
  const void* adj = d_in[1];
  const float* W = (const float*)d_in[2];
  const float* a = (const float*)d_in[3];
  const float* gamma = (const float*)d_in[4];
  const float* beta = (const float*)d_in[5];
  float* out = (float*)d_out;

  char* ws = (char*)d_ws;
  int* flag = (int*)ws;
  unsigned short* Wh = (unsigned short*)(ws + 256);                // 8 MB
  unsigned short* Wt2 = (unsigned short*)(ws + 256 + 8388608);     // 512 KB
  float* e_src = (float*)(ws + 256 + 8388608 + 524288);            // 256 KB
  float* e_dst = e_src + (size_t)BB * NN * HH;                     // 256 KB

  k_prep2<<<dim3(16, 8), 256, 0, stream>>>(W, Wt2, adj, flag);
  k_gemm4<<<dim3(256, 2), 256, 0, stream>>>(x, Wt2, a, Wh, e_src, e_dst);
  k_attn<<<2048, 256, 0, stream>>>(x, adj, flag, Wh, e_src, e_dst, gamma,
                                   beta, out);
}